// Round 4
// baseline (200.998 us; speedup 1.0000x reference)
//
#include <hip/hip_runtime.h>
#include <stdint.h>
#include <stddef.h>

#define NROWS 8192
#define DIM   1024
#define TEMP  10.0f

#define BM 256
#define BN 128
#define BK 128

typedef __attribute__((ext_vector_type(8))) int i32x8;
typedef __attribute__((ext_vector_type(4))) float floatx4;

// async 16B global->LDS (global_load_lds_dwordx4); LDS dest is wave-uniform
// base + lane*16 -- staging dest is t*16 by construction.
__device__ __forceinline__ void load16_lds(const unsigned char* g, unsigned char* l) {
    __builtin_amdgcn_global_load_lds(
        (__attribute__((address_space(1))) void*)(g),
        (__attribute__((address_space(3))) void*)(l),
        16, 0, 0);
}

__device__ __forceinline__ i32x8 pack8(int4 lo, int4 hi) {
    i32x8 r;
    r[0] = lo.x; r[1] = lo.y; r[2] = lo.z; r[3] = lo.w;
    r[4] = hi.x; r[5] = hi.y; r[6] = hi.z; r[7] = hi.w;
    return r;
}

// Wave-per-row L2 normalize + fp32 -> fp8 e4m3 (OCP). Each lane owns 16
// contiguous elements: 4x float4 load, 1x int4 store. No LDS, no barriers.
__global__ __launch_bounds__(256) void normalize_kernel(
    const float* __restrict__ img, const float* __restrict__ txt,
    unsigned char* __restrict__ imgq, unsigned char* __restrict__ txtq,
    float* __restrict__ out)
{
    const int gw = blockIdx.x * 4 + (threadIdx.x >> 6);   // row id, 0..16383
    const int lane = threadIdx.x & 63;
    const float* src;
    unsigned char* dst;
    if (gw < NROWS) {
        src = img + (size_t)gw * DIM;
        dst = imgq + (size_t)gw * DIM;
    } else {
        src = txt + (size_t)(gw - NROWS) * DIM;
        dst = txtq + (size_t)(gw - NROWS) * DIM;
    }
    float4 v[4];
    float ss = 0.f;
#pragma unroll
    for (int c = 0; c < 4; c++) {
        v[c] = ((const float4*)src)[lane * 4 + c];
        ss += v[c].x * v[c].x + v[c].y * v[c].y + v[c].z * v[c].z + v[c].w * v[c].w;
    }
#pragma unroll
    for (int off = 32; off; off >>= 1) ss += __shfl_xor(ss, off);
    const float scale = 1.0f / fmaxf(sqrtf(ss), 1e-12f);
    int4 o;
    int* op = (int*)&o;
#pragma unroll
    for (int c = 0; c < 4; c++) {
        int p = 0;
        p = __builtin_amdgcn_cvt_pk_fp8_f32(v[c].x * scale, v[c].y * scale, p, false);
        p = __builtin_amdgcn_cvt_pk_fp8_f32(v[c].z * scale, v[c].w * scale, p, true);
        op[c] = p;
    }
    ((int4*)dst)[lane] = o;
    if (gw == 0 && lane == 0) out[0] = 0.f;   // zero the atomic target
}

// 256x128 tile NT-GEMM on fp8 e4m3 via MX-scaled MFMA 16x16x128 (unit
// scales), BK=128, fully unrolled 8-iter K-loop. 4 waves (2x2), wave tile
// 128x64. A staged via global_load_lds into 16B-XOR-swizzled LDS; B frags
// read DIRECTLY from global/L2 (coalesced 32B/lane), prefetched one K-iter
// ahead into a 2-deep register buffer -- independent of the barrier drain.
// XCD-aware block swizzle keeps each XCD's A/B working set in its 4MB L2.
// Fused sigmoid-loss epilogue + reduction (sim matrix never materialized).
__global__ __launch_bounds__(256, 2) void simloss_kernel(
    const unsigned char* __restrict__ An,   // img normalized fp8 [8192][1024]
    const unsigned char* __restrict__ Bn,   // txt normalized fp8 [8192][1024]
    const float* __restrict__ bias,
    float* __restrict__ out)
{
    __shared__ unsigned char As[BM * BK];   // 32 KB, [row][k16-swizzled]

    const int t = threadIdx.x;
    const int lane = t & 63;
    const int wave = t >> 6;

    // XCD-aware swizzle: xcd = bid&7 owns y in {xcd, xcd+8, ..., xcd+56};
    // within an XCD, y cycles fast, x slow -> A-tile reused 8x while hot.
    const int bid = blockIdx.x;
    const int blockN = (bid & 7) + 8 * ((bid >> 3) & 7);   // 0..63
    const int blockM = bid >> 6;                            // 0..31

    // A staging: thread t -> LDS row (t>>3)+32c, slot t&7; source chunk
    // g = slot ^ (row&7)  (16B-granular XOR swizzle)
    const int srow = t >> 3;                       // 0..31
    const int g = (t & 7) ^ ((t >> 3) & 7);
    const unsigned char* gA = An + (size_t)(blockM * BM + srow) * DIM + g * 16;
    unsigned char* lA = &As[t * 16];

    // wave tile: 2x2 waves, each 128x64 output (mi 0..7, ni 0..3)
    const int waveM = (wave >> 1) * 128;
    const int waveN = (wave & 1) * 64;
    const int fr = lane & 15;    // row/col within 16x16 fragment
    const int fq = lane >> 4;    // quad: holds k in [32fq, 32fq+32)
    const int o0 = ((2 * fq) ^ (fr & 7)) * 16;

    // B fragment base: row = blockN*128 + waveN + ni*16 + fr, k = 32*fq
    const unsigned char* Bb = Bn + (size_t)(blockN * BN + waveN + fr) * DIM + 32 * fq;

    floatx4 acc[8][4];
#pragma unroll
    for (int mi = 0; mi < 8; mi++)
#pragma unroll
        for (int ni = 0; ni < 4; ni++)
            acc[mi][ni] = (floatx4){0.f, 0.f, 0.f, 0.f};

    int4 bl[2][4], bh[2][4];
#pragma unroll
    for (int ni = 0; ni < 4; ni++) {
        bl[0][ni] = *(const int4*)(Bb + (size_t)ni * 16 * DIM);
        bh[0][ni] = *(const int4*)(Bb + (size_t)ni * 16 * DIM + 16);
    }

#pragma unroll
    for (int it = 0; it < DIM / BK; it++) {
        const int k0 = it * BK;
        const int cur = it & 1, nxt = cur ^ 1;
        __syncthreads();   // previous iter's A reads done
#pragma unroll
        for (int c = 0; c < 8; c++)
            load16_lds(gA + (size_t)c * 32 * DIM + k0, lA + c * 4096);
        asm volatile("s_waitcnt vmcnt(0)" ::: "memory");
        __syncthreads();   // staged A tile visible

        // prefetch next iter's B frags (completes during this iter's MFMAs)
        if (it < DIM / BK - 1) {
#pragma unroll
            for (int ni = 0; ni < 4; ni++) {
                bl[nxt][ni] = *(const int4*)(Bb + (size_t)ni * 16 * DIM + k0 + BK);
                bh[nxt][ni] = *(const int4*)(Bb + (size_t)ni * 16 * DIM + k0 + BK + 16);
            }
        }

#pragma unroll
        for (int mi = 0; mi < 8; mi++) {
            const int row = waveM + mi * 16 + fr;
            i32x8 a = pack8(*(const int4*)&As[row * BK + o0],
                            *(const int4*)&As[row * BK + (o0 ^ 16)]);
#pragma unroll
            for (int ni = 0; ni < 4; ni++)
                acc[mi][ni] = __builtin_amdgcn_mfma_scale_f32_16x16x128_f8f6f4(
                    a, pack8(bl[cur][ni], bh[cur][ni]), acc[mi][ni],
                    0, 0,                 // cbsz=FP8(e4m3), blgp=FP8(e4m3)
                    0, 0x7f7f7f7f,        // opsel_a, scale_a = 2^0
                    0, 0x7f7f7f7f);       // opsel_b, scale_b = 2^0
        }
    }

    // fused epilogue: logit = -10*sim + bias; label = +1 diag else -1;
    // contribution = softplus(label*logit). C/D map (shape-determined):
    // col=lane&15, row=fq*4+r; final scalar is transpose-invariant.
    const float biasv = bias[0];
    float local = 0.f;
    const int gi0 = blockM * BM + waveM + fq * 4;
    const int gj0 = blockN * BN + waveN + fr;
#pragma unroll
    for (int mi = 0; mi < 8; mi++) {
#pragma unroll
        for (int ni = 0; ni < 4; ni++) {
            const int jg = gj0 + ni * 16;
#pragma unroll
            for (int r = 0; r < 4; r++) {
                float sim = acc[mi][ni][r];
                float logit = fmaf(sim, -TEMP, biasv);
                int ig = gi0 + mi * 16 + r;
                float x = (ig == jg) ? logit : -logit;
                // softplus(x) = max(x,0) + log(1+exp(-|x|))
                local += fmaxf(x, 0.f) + __logf(1.0f + __expf(-fabsf(x)));
            }
        }
    }
#pragma unroll
    for (int off = 32; off; off >>= 1) local += __shfl_xor(local, off);
    __shared__ float red[4];
    if (lane == 0) red[wave] = local;
    __syncthreads();
    if (t == 0) {
        float tot = (red[0] + red[1] + red[2] + red[3]) * (1.0f / 8192.0f);
        atomicAdd(out, tot);
    }
}

extern "C" void kernel_launch(void* const* d_in, const int* in_sizes, int n_in,
                              void* d_out, int out_size, void* d_ws, size_t ws_size,
                              hipStream_t stream) {
    const float* txt = (const float*)d_in[0];   // text_embeddings [8192][1024]
    const float* img = (const float*)d_in[1];   // image_embeddings [8192][1024]
    const float* bias = (const float*)d_in[2];  // [1]
    float* out = (float*)d_out;

    unsigned char* imgq = (unsigned char*)d_ws;                      // 8 MB fp8
    unsigned char* txtq = imgq + (size_t)NROWS * DIM;                // 8 MB fp8

    normalize_kernel<<<dim3(2 * NROWS / 4), dim3(256), 0, stream>>>(
        img, txt, imgq, txtq, out);

    simloss_kernel<<<dim3((NROWS / BM) * (NROWS / BN)), dim3(256), 0, stream>>>(
        imgq, txtq, bias, out);
}

// Round 5
// 168.560 us; speedup vs baseline: 1.1924x; 1.1924x over previous
//
#include <hip/hip_runtime.h>
#include <stdint.h>
#include <stddef.h>

#define NROWS 8192
#define DIM   1024
#define TEMP  10.0f

#define BM 256
#define BN 128
#define BK 128

typedef __attribute__((ext_vector_type(8))) int i32x8;
typedef __attribute__((ext_vector_type(4))) float floatx4;

// async 16B global->LDS (global_load_lds_dwordx4); LDS dest is wave-uniform
// base + lane*16 -- staging dest is t*16 by construction.
__device__ __forceinline__ void load16_lds(const unsigned char* g, unsigned char* l) {
    __builtin_amdgcn_global_load_lds(
        (__attribute__((address_space(1))) void*)(g),
        (__attribute__((address_space(3))) void*)(l),
        16, 0, 0);
}

__device__ __forceinline__ i32x8 pack8(int4 lo, int4 hi) {
    i32x8 r;
    r[0] = lo.x; r[1] = lo.y; r[2] = lo.z; r[3] = lo.w;
    r[4] = hi.x; r[5] = hi.y; r[6] = hi.z; r[7] = hi.w;
    return r;
}

// Wave-per-row L2 normalize + fp32 -> fp8 e4m3 (OCP). Each lane owns 16
// contiguous elements: 4x float4 load, 1x int4 store. No LDS, no barriers.
__global__ __launch_bounds__(256) void normalize_kernel(
    const float* __restrict__ img, const float* __restrict__ txt,
    unsigned char* __restrict__ imgq, unsigned char* __restrict__ txtq,
    float* __restrict__ out)
{
    const int gw = blockIdx.x * 4 + (threadIdx.x >> 6);   // row id, 0..16383
    const int lane = threadIdx.x & 63;
    const float* src;
    unsigned char* dst;
    if (gw < NROWS) {
        src = img + (size_t)gw * DIM;
        dst = imgq + (size_t)gw * DIM;
    } else {
        src = txt + (size_t)(gw - NROWS) * DIM;
        dst = txtq + (size_t)(gw - NROWS) * DIM;
    }
    float4 v[4];
    float ss = 0.f;
#pragma unroll
    for (int c = 0; c < 4; c++) {
        v[c] = ((const float4*)src)[lane * 4 + c];
        ss += v[c].x * v[c].x + v[c].y * v[c].y + v[c].z * v[c].z + v[c].w * v[c].w;
    }
#pragma unroll
    for (int off = 32; off; off >>= 1) ss += __shfl_xor(ss, off);
    const float scale = 1.0f / fmaxf(sqrtf(ss), 1e-12f);
    int4 o;
    int* op = (int*)&o;
#pragma unroll
    for (int c = 0; c < 4; c++) {
        int p = 0;
        p = __builtin_amdgcn_cvt_pk_fp8_f32(v[c].x * scale, v[c].y * scale, p, false);
        p = __builtin_amdgcn_cvt_pk_fp8_f32(v[c].z * scale, v[c].w * scale, p, true);
        op[c] = p;
    }
    ((int4*)dst)[lane] = o;
    if (gw == 0 && lane == 0) out[0] = 0.f;   // zero the atomic target
}

// 256x128 tile NT-GEMM on fp8 e4m3 via MX-scaled MFMA 16x16x128 (unit
// scales), BK=128, 8 K-iters. 4 waves (2x2), wave tile 128x64. A + B staged
// via global_load_lds into 16B-XOR-swizzled LDS; B double-buffered so its
// loads stay in flight across the barrier (wait is vmcnt(4): only A drains).
// Branch-free softplus epilogue using the identity
//   softplus(x) = (x+|x|)/2 + log(1+e^-|x|),  sum(x)/2 linear in the sims.
__global__ __launch_bounds__(256, 2) void simloss_kernel(
    const unsigned char* __restrict__ An,   // img normalized fp8 [8192][1024]
    const unsigned char* __restrict__ Bn,   // txt normalized fp8 [8192][1024]
    const float* __restrict__ bias,
    float* __restrict__ out)
{
    __shared__ unsigned char As[BM * BK];        // 32 KB, [row][k16-swizzled]
    __shared__ unsigned char Bs[2][BN * BK];     // 2 x 16 KB (double buffer)
    __shared__ float red[12];

    const int t = threadIdx.x;
    const int lane = t & 63;
    const int wave = t >> 6;

    // XCD-aware swizzle: xcd = bid&7 owns y in {xcd, xcd+8, ..., xcd+56}
    const int bid = blockIdx.x;
    const int blockN = (bid & 7) + 8 * ((bid >> 3) & 7);   // 0..63
    const int blockM = bid >> 6;                            // 0..31

    // staging: thread t -> LDS row (t>>3)+32c, slot t&7; source chunk
    // g = slot ^ (row&7)  (16B-granular XOR swizzle)
    const int srow = t >> 3;                       // 0..31
    const int g = (t & 7) ^ ((t >> 3) & 7);
    const unsigned char* gA = An + (size_t)(blockM * BM + srow) * DIM + g * 16;
    const unsigned char* gB = Bn + (size_t)(blockN * BN + srow) * DIM + g * 16;
    unsigned char* lA = &As[t * 16];

    // wave tile: 2x2 waves, each 128x64 output (mi 0..7, ni 0..3)
    const int waveM = (wave >> 1) * 128;
    const int waveN = (wave & 1) * 64;
    const int fr = lane & 15;    // row/col within 16x16 fragment
    const int fq = lane >> 4;    // quad: holds k in [32fq, 32fq+32)
    const int o0 = ((2 * fq) ^ (fr & 7)) * 16;

    floatx4 acc[8][4];
#pragma unroll
    for (int mi = 0; mi < 8; mi++)
#pragma unroll
        for (int ni = 0; ni < 4; ni++)
            acc[mi][ni] = (floatx4){0.f, 0.f, 0.f, 0.f};

    // prologue: B tile for iter 0 into buffer 0
#pragma unroll
    for (int c = 0; c < 4; c++)
        load16_lds(gB + (size_t)c * 32 * DIM, &Bs[0][t * 16 + c * 4096]);

#pragma unroll
    for (int it = 0; it < DIM / BK; it++) {
        const int k0 = it * BK;
        const int cur = it & 1;
        __syncthreads();   // prev iter's LDS reads done by all waves
#pragma unroll
        for (int c = 0; c < 8; c++)
            load16_lds(gA + (size_t)c * 32 * DIM + k0, lA + c * 4096);
        if (it < DIM / BK - 1) {
#pragma unroll
            for (int c = 0; c < 4; c++)
                load16_lds(gB + (size_t)c * 32 * DIM + k0 + BK,
                           &Bs[cur ^ 1][t * 16 + c * 4096]);
            // wait for B(it) [4 oldest] + A(it) [8]; B(it+1) stays in flight
            asm volatile("s_waitcnt vmcnt(4)" ::: "memory");
        } else {
            asm volatile("s_waitcnt vmcnt(0)" ::: "memory");
        }
        __syncthreads();   // staged tile visible

        asm volatile("s_setprio 1");
        i32x8 b[4];
#pragma unroll
        for (int ni = 0; ni < 4; ni++) {
            const int row = waveN + ni * 16 + fr;
            b[ni] = pack8(*(const int4*)&Bs[cur][row * BK + o0],
                          *(const int4*)&Bs[cur][row * BK + (o0 ^ 16)]);
        }
#pragma unroll
        for (int mi = 0; mi < 8; mi++) {
            const int row = waveM + mi * 16 + fr;
            i32x8 a = pack8(*(const int4*)&As[row * BK + o0],
                            *(const int4*)&As[row * BK + (o0 ^ 16)]);
#pragma unroll
            for (int ni = 0; ni < 4; ni++)
                acc[mi][ni] = __builtin_amdgcn_mfma_scale_f32_16x16x128_f8f6f4(
                    a, b[ni], acc[mi][ni],
                    0, 0,                 // cbsz=FP8(e4m3), blgp=FP8(e4m3)
                    0, 0x7f7f7f7f,        // opsel_a, scale_a = 2^0
                    0, 0x7f7f7f7f);       // opsel_b, scale_b = 2^0
        }
        asm volatile("s_setprio 0");
    }

    // Branch-free epilogue. logit = -10*sim + b, x = label*logit.
    //   softplus(x) = (x+|x|)/2 + log(1+e^-|x|)
    //   sum(x)/2 = sum_diag(logit) - sum_all(logit)/2   (linear!)
    // Work in log2 domain: w = logit*log2e, so e^-|logit| = 2^-|w| and
    //   sum softplus = ln2 * sum(log2(1+2^-|w|) + |w|/2) + sum(x)/2.
    const float bv = bias[0];
    const float c1 = -TEMP * 1.4426950408889634f;   // -10*log2e
    const float c0 = bv * 1.4426950408889634f;
    float accP = 0.f, accQ = 0.f, accD = 0.f;
    const int gi0 = blockM * BM + waveM + fq * 4;
    const int gj0 = blockN * BN + waveN + fr;
#pragma unroll
    for (int mi = 0; mi < 8; mi++) {
#pragma unroll
        for (int ni = 0; ni < 4; ni++) {
#pragma unroll
            for (int r = 0; r < 4; r++) {
                float s = acc[mi][ni][r];
                float w = fmaf(s, c1, c0);
                float e2 = __builtin_amdgcn_exp2f(-fabsf(w));
                accP += __builtin_amdgcn_logf(1.0f + e2);   // v_log = log2
                accP = fmaf(0.5f, fabsf(w), accP);
                accQ += s;
            }
        }
    }
    // diagonal sims (only 64 of 2048 blocks contain diagonal elements)
    const bool diagblk = ((blockN >> 1) == blockM);
    if (diagblk) {
#pragma unroll
        for (int mi = 0; mi < 8; mi++)
#pragma unroll
            for (int ni = 0; ni < 4; ni++)
#pragma unroll
                for (int r = 0; r < 4; r++) {
                    int ig = gi0 + mi * 16 + r;
                    int jg = gj0 + ni * 16;
                    if (ig == jg) accD += acc[mi][ni][r];
                }
    }
#pragma unroll
    for (int off = 32; off; off >>= 1) {
        accP += __shfl_xor(accP, off);
        accQ += __shfl_xor(accQ, off);
        accD += __shfl_xor(accD, off);
    }
    if (lane == 0) {
        red[wave * 3 + 0] = accP;
        red[wave * 3 + 1] = accQ;
        red[wave * 3 + 2] = accD;
    }
    __syncthreads();
    if (t == 0) {
        float P = red[0] + red[3] + red[6] + red[9];
        float Q = red[1] + red[4] + red[7] + red[10];
        float D = red[2] + red[5] + red[8] + red[11];
        // sum softplus over this block's 256x128 sims:
        //   ln2*P  +  [5*Q - 16384*b]  (+ diag part: -10*D + 128*b)
        float contrib = fmaf(0.6931471805599453f, P, fmaf(5.0f, Q, -16384.0f * bv));
        if (diagblk) contrib += fmaf(-TEMP, D, 128.0f * bv);
        atomicAdd(out, contrib * (1.0f / 8192.0f));
    }
}

extern "C" void kernel_launch(void* const* d_in, const int* in_sizes, int n_in,
                              void* d_out, int out_size, void* d_ws, size_t ws_size,
                              hipStream_t stream) {
    const float* txt = (const float*)d_in[0];   // text_embeddings [8192][1024]
    const float* img = (const float*)d_in[1];   // image_embeddings [8192][1024]
    const float* bias = (const float*)d_in[2];  // [1]
    float* out = (float*)d_out;

    unsigned char* imgq = (unsigned char*)d_ws;                      // 8 MB fp8
    unsigned char* txtq = imgq + (size_t)NROWS * DIM;                // 8 MB fp8

    normalize_kernel<<<dim3(2 * NROWS / 4), dim3(256), 0, stream>>>(
        img, txt, imgq, txtq, out);

    simloss_kernel<<<dim3((NROWS / BM) * (NROWS / BN)), dim3(256), 0, stream>>>(
        imgq, txtq, bias, out);
}

// Round 6
// 162.603 us; speedup vs baseline: 1.2361x; 1.0366x over previous
//
#include <hip/hip_runtime.h>
#include <stdint.h>
#include <stddef.h>

#define NROWS 8192
#define DIM   1024
#define TEMP  10.0f

#define BM 256
#define BN 128
#define BK 128

typedef __attribute__((ext_vector_type(8))) int i32x8;
typedef __attribute__((ext_vector_type(16))) float floatx16;

// async 16B global->LDS (global_load_lds_dwordx4); LDS dest is wave-uniform
// base + lane*16 -- staging dest is t*16 by construction.
__device__ __forceinline__ void load16_lds(const unsigned char* g, unsigned char* l) {
    __builtin_amdgcn_global_load_lds(
        (__attribute__((address_space(1))) void*)(g),
        (__attribute__((address_space(3))) void*)(l),
        16, 0, 0);
}

// Load a 32B fragment (k in [kb, kb+32) of a row) from the 16B-XOR-swizzled
// LDS tile. kb4 = kb>>4 (even); slot(k16) = k16 ^ (row&7). The two b128s
// land directly in the i32x8's storage (no repack movs). Bank math: per
// 16-lane phase, 8 slots x 2 lanes (2-way = free), all 32 banks covered.
__device__ __forceinline__ i32x8 ldfrag(const unsigned char* rowbase, int r7, int kb4) {
    const int o0 = (kb4 ^ r7) << 4;
    union { i32x8 v; int4 q[2]; } u;
    u.q[0] = *(const int4*)(rowbase + o0);
    u.q[1] = *(const int4*)(rowbase + (o0 ^ 16));
    return u.v;
}

// Wave-per-row L2 normalize + fp32 -> fp8 e4m3 (OCP). Coalesced float4
// loads (lane+64c) and coalesced dword stores. No LDS, no barriers.
__global__ __launch_bounds__(256) void normalize_kernel(
    const float* __restrict__ img, const float* __restrict__ txt,
    unsigned char* __restrict__ imgq, unsigned char* __restrict__ txtq,
    float* __restrict__ out)
{
    const int gw = blockIdx.x * 4 + (threadIdx.x >> 6);   // row id, 0..16383
    const int lane = threadIdx.x & 63;
    const float* src;
    unsigned char* dst;
    if (gw < NROWS) {
        src = img + (size_t)gw * DIM;
        dst = imgq + (size_t)gw * DIM;
    } else {
        src = txt + (size_t)(gw - NROWS) * DIM;
        dst = txtq + (size_t)(gw - NROWS) * DIM;
    }
    float4 v[4];
    float ss = 0.f;
#pragma unroll
    for (int c = 0; c < 4; c++) {
        v[c] = ((const float4*)src)[lane + 64 * c];
        ss += v[c].x * v[c].x + v[c].y * v[c].y + v[c].z * v[c].z + v[c].w * v[c].w;
    }
#pragma unroll
    for (int off = 32; off; off >>= 1) ss += __shfl_xor(ss, off);
    const float scale = 1.0f / fmaxf(sqrtf(ss), 1e-12f);
#pragma unroll
    for (int c = 0; c < 4; c++) {
        int p = 0;
        p = __builtin_amdgcn_cvt_pk_fp8_f32(v[c].x * scale, v[c].y * scale, p, false);
        p = __builtin_amdgcn_cvt_pk_fp8_f32(v[c].z * scale, v[c].w * scale, p, true);
        ((int*)dst)[lane + 64 * c] = p;
    }
    if (gw == 0 && lane == 0) out[0] = 0.f;   // zero the atomic target
}

// 256x128 tile NT-GEMM on fp8 e4m3 via MX-scaled MFMA 32x32x64 (unit
// scales), BK=128 = 2 k-steps/iter, 8 K-iters. 4 waves (2x2), wave tile
// 128x64 as 4x2 of 32x32 (acc = 8 x floatx16 = 128 regs). A+B staged via
// global_load_lds into 16B-XOR-swizzled LDS; B double-buffered so its loads
// stay in flight across the barrier (wait = vmcnt(4): only A drains).
// Branch-free softplus epilogue: softplus(x) = (x+|x|)/2 + log(1+e^-|x|),
// with sum(x)/2 linear in the sims (only diag + totals needed).
__global__ __launch_bounds__(256, 2) void simloss_kernel(
    const unsigned char* __restrict__ An,   // img normalized fp8 [8192][1024]
    const unsigned char* __restrict__ Bn,   // txt normalized fp8 [8192][1024]
    const float* __restrict__ bias,
    float* __restrict__ out)
{
    __shared__ unsigned char As[BM * BK];        // 32 KB, [row][k16-swizzled]
    __shared__ unsigned char Bs[2][BN * BK];     // 2 x 16 KB (double buffer)
    __shared__ float red[12];

    const int t = threadIdx.x;
    const int lane = t & 63;
    const int wave = t >> 6;

    // XCD-aware swizzle: xcd = bid&7 owns y in {xcd, xcd+8, ..., xcd+56}
    const int bid = blockIdx.x;
    const int blockN = (bid & 7) + 8 * ((bid >> 3) & 7);   // 0..63
    const int blockM = bid >> 6;                            // 0..31

    // staging: thread t -> LDS row (t>>3)+32c, slot t&7; source chunk
    // g = slot ^ (row&7)  (16B-granular XOR swizzle)
    const int srow = t >> 3;                       // 0..31
    const int g = (t & 7) ^ ((t >> 3) & 7);
    const unsigned char* gA = An + (size_t)(blockM * BM + srow) * DIM + g * 16;
    const unsigned char* gB = Bn + (size_t)(blockN * BN + srow) * DIM + g * 16;
    unsigned char* lA = &As[t * 16];

    // wave tile: 2x2 waves, each 128x64 (mi 0..3, ni 0..1 of 32x32 tiles)
    const int waveM = (wave >> 1) * 128;
    const int waveN = (wave & 1) * 64;
    const int fr = lane & 31;    // row within 32-row operand tile
    const int fh = lane >> 5;    // half: holds k in [32*fh, 32*fh+32)

    // per-lane row bases into LDS (loop-invariant)
    const unsigned char* arow[4];
    const unsigned char* brow0[2];
    int ar7[4], br7[2];
#pragma unroll
    for (int mi = 0; mi < 4; mi++) {
        const int r = waveM + mi * 32 + fr;
        arow[mi] = &As[r * BK];
        ar7[mi] = r & 7;
    }
#pragma unroll
    for (int ni = 0; ni < 2; ni++) {
        const int r = waveN + ni * 32 + fr;
        brow0[ni] = &Bs[0][r * BK];
        br7[ni] = r & 7;
    }

    floatx16 acc[4][2];
#pragma unroll
    for (int mi = 0; mi < 4; mi++)
#pragma unroll
        for (int ni = 0; ni < 2; ni++)
            acc[mi][ni] = (floatx16)(0.f);

    // prologue: B tile for iter 0 into buffer 0
#pragma unroll
    for (int c = 0; c < 4; c++)
        load16_lds(gB + (size_t)c * 32 * DIM, &Bs[0][t * 16 + c * 4096]);

#pragma unroll
    for (int it = 0; it < DIM / BK; it++) {
        const int k0 = it * BK;
        const int cur = it & 1;
        __syncthreads();   // prev iter's LDS reads done by all waves
#pragma unroll
        for (int c = 0; c < 8; c++)
            load16_lds(gA + (size_t)c * 32 * DIM + k0, lA + c * 4096);
        if (it < DIM / BK - 1) {
#pragma unroll
            for (int c = 0; c < 4; c++)
                load16_lds(gB + (size_t)c * 32 * DIM + k0 + BK,
                           &Bs[cur ^ 1][t * 16 + c * 4096]);
            // wait for B(it) [oldest] + A(it) [8]; B(it+1) stays in flight
            asm volatile("s_waitcnt vmcnt(4)" ::: "memory");
        } else {
            asm volatile("s_waitcnt vmcnt(0)" ::: "memory");
        }
        __syncthreads();   // staged tile visible

        asm volatile("s_setprio 1");
        const int boff = cur * (BN * BK);
#pragma unroll
        for (int ks = 0; ks < 2; ks++) {
            const int kb4 = ks * 4 + fh * 2;   // (k-byte offset)>>4, even
            i32x8 b[2];
#pragma unroll
            for (int ni = 0; ni < 2; ni++)
                b[ni] = ldfrag(brow0[ni] + boff, br7[ni], kb4);
#pragma unroll
            for (int mi = 0; mi < 4; mi++) {
                i32x8 a = ldfrag(arow[mi], ar7[mi], kb4);
#pragma unroll
                for (int ni = 0; ni < 2; ni++)
                    acc[mi][ni] = __builtin_amdgcn_mfma_scale_f32_32x32x64_f8f6f4(
                        a, b[ni], acc[mi][ni],
                        0, 0,                 // cbsz=FP8(e4m3), blgp=FP8(e4m3)
                        0, 0x7f7f7f7f,        // opsel_a, scale_a = 2^0
                        0, 0x7f7f7f7f);       // opsel_b, scale_b = 2^0
            }
        }
        asm volatile("s_setprio 0");
    }

    // Branch-free epilogue. logit = -10*sim + b, x = label*logit.
    //   softplus(x) = (x+|x|)/2 + log(1+e^-|x|)
    //   sum(x)/2 = sum_diag(logit) - sum_all(logit)/2   (linear!)
    // log2 domain: w = logit*log2e; sum softplus =
    //   ln2 * sum(log2(1+2^-|w|) + |w|/2) + sum(x)/2.
    const float bv = bias[0];
    const float c1 = -TEMP * 1.4426950408889634f;   // -10*log2e
    const float c0 = bv * 1.4426950408889634f;
    float accP = 0.f, accQ = 0.f, accD = 0.f;
    // C/D map (32x32, verified): col = lane&31 (=j/txt), row = (reg&3) +
    // 8*(reg>>2) + 4*(lane>>5) (=i/img); final scalar transpose-invariant.
    const int gi0 = blockM * BM + waveM + 4 * fh;
    const int gj0 = blockN * BN + waveN + fr;
#pragma unroll
    for (int mi = 0; mi < 4; mi++) {
#pragma unroll
        for (int ni = 0; ni < 2; ni++) {
#pragma unroll
            for (int reg = 0; reg < 16; reg++) {
                float s = acc[mi][ni][reg];
                float w = fmaf(s, c1, c0);
                float e2 = __builtin_amdgcn_exp2f(-fabsf(w));
                accP += __builtin_amdgcn_logf(1.0f + e2);   // v_log = log2
                accP = fmaf(0.5f, fabsf(w), accP);
                accQ += s;
            }
        }
    }
    // diagonal sims (only 64 of 2048 blocks contain diagonal elements)
    const bool diagblk = ((blockN >> 1) == blockM);
    if (diagblk) {
#pragma unroll
        for (int mi = 0; mi < 4; mi++)
#pragma unroll
            for (int ni = 0; ni < 2; ni++)
#pragma unroll
                for (int reg = 0; reg < 16; reg++) {
                    int ig = gi0 + mi * 32 + (reg & 3) + 8 * (reg >> 2);
                    int jg = gj0 + ni * 32;
                    if (ig == jg) accD += acc[mi][ni][reg];
                }
    }
#pragma unroll
    for (int off = 32; off; off >>= 1) {
        accP += __shfl_xor(accP, off);
        accQ += __shfl_xor(accQ, off);
        accD += __shfl_xor(accD, off);
    }
    if (lane == 0) {
        red[wave * 3 + 0] = accP;
        red[wave * 3 + 1] = accQ;
        red[wave * 3 + 2] = accD;
    }
    __syncthreads();
    if (t == 0) {
        float P = red[0] + red[3] + red[6] + red[9];
        float Q = red[1] + red[4] + red[7] + red[10];
        float D = red[2] + red[5] + red[8] + red[11];
        // sum softplus over this block's 256x128 sims:
        //   ln2*P + [5*Q - 16384*b]  (+ diag part: -10*D + 128*b)
        float contrib = fmaf(0.6931471805599453f, P, fmaf(5.0f, Q, -16384.0f * bv));
        if (diagblk) contrib += fmaf(-TEMP, D, 128.0f * bv);
        atomicAdd(out, contrib * (1.0f / 8192.0f));
    }
}

extern "C" void kernel_launch(void* const* d_in, const int* in_sizes, int n_in,
                              void* d_out, int out_size, void* d_ws, size_t ws_size,
                              hipStream_t stream) {
    const float* txt = (const float*)d_in[0];   // text_embeddings [8192][1024]
    const float* img = (const float*)d_in[1];   // image_embeddings [8192][1024]
    const float* bias = (const float*)d_in[2];  // [1]
    float* out = (float*)d_out;

    unsigned char* imgq = (unsigned char*)d_ws;                      // 8 MB fp8
    unsigned char* txtq = imgq + (size_t)NROWS * DIM;                // 8 MB fp8

    normalize_kernel<<<dim3(2 * NROWS / 4), dim3(256), 0, stream>>>(
        img, txt, imgq, txtq, out);

    simloss_kernel<<<dim3((NROWS / BM) * (NROWS / BN)), dim3(256), 0, stream>>>(
        imgq, txtq, bias, out);
}